// Round 11
// baseline (190.464 us; speedup 1.0000x reference)
//
#include <hip/hip_runtime.h>
#include <hip/hip_bf16.h>

// Problem constants
#define NB   32      // batch
#define NC   24      // image channels
#define ND   12      // spatial
#define NN   144     // ND*ND objects
#define QD   11
#define GH   256
#define FOUT 10

typedef unsigned short u16;
typedef __attribute__((ext_vector_type(8))) short bf16x8;
typedef __attribute__((ext_vector_type(4))) float f32x4;

// Workspace layout (u16 units unless noted):
//   Lqb  u16 [32][144][256]  off 0          (= L + q@Wg1_q + bg1, bf16)
//   Rb   u16 [32][144][256]  off 1179648
//   Bswz u16 [128][64][8]    off 2359296    (MFMA B-fragment order)
//   S    f32 [32][256]       byte-off 4849664
#define LQ_U16  0
#define R_U16   1179648
#define BS_U16  2359296
#define S_BYTE  4849664

__device__ inline float b2f(u16 v) {
  union { unsigned u; float f; } c; c.u = ((unsigned)v) << 16; return c.f;
}
__device__ inline u16 f2b(float f) {
  __hip_bfloat16 h = __float2bfloat16(f);
  return *reinterpret_cast<u16*>(&h);
}

// ---------------------------------------------------------------------------
// Fused prep:
//  blocks [0, 9216): per-object projections -> bf16 (Lq folds q-term + bg1).
//  blocks [9216, 9472): Wg2 -> bf16 B-fragment swizzle; zero S.
// ---------------------------------------------------------------------------
__global__ __launch_bounds__(256) void prep(const float* __restrict__ image,
                                            const float* __restrict__ question,
                                            const float* __restrict__ Wg1,
                                            const float* __restrict__ bg1,
                                            const float* __restrict__ Wg2,
                                            u16* __restrict__ Lq,
                                            u16* __restrict__ R,
                                            float* __restrict__ S,
                                            u16* __restrict__ Bswz) {
  int blk = blockIdx.x;
  int h   = threadIdx.x;
  if (blk < 2 * NB * NN) {
    int p     = blk % NN;
    int rest2 = blk / NN;
    int b     = rest2 & (NB - 1);
    int which = rest2 >> 5;
    const float* Wrow = Wg1 + which * (NC + 2) * GH;
    const float* img  = image + b * (NC * NN) + p;
    float acc = 0.f;
#pragma unroll
    for (int c = 0; c < NC; ++c) acc += img[c * NN] * Wrow[c * GH + h];
    int i = p / ND, j = p - i * ND;
    const float inv = 1.0f / (ND - 1);
    acc += (j * inv) * Wrow[24 * GH + h];
    acc += (i * inv) * Wrow[25 * GH + h];
    if (which == 0) {
      acc += bg1[h];
#pragma unroll
      for (int tq = 0; tq < QD; ++tq)
        acc += question[b * QD + tq] * Wg1[(2 * (NC + 2) + tq) * GH + h];
      Lq[(b * NN + p) * GH + h] = f2b(acc);
    } else {
      R[(b * NN + p) * GH + h] = f2b(acc);
    }
  } else {
    int tid = (blk - 2 * NB * NN) * 256 + h;   // 0..65535
    int e   = tid & 7;
    int l   = (tid >> 3) & 63;
    int fid = tid >> 9;
    int kt  = fid >> 4, nt = fid & 15;
    int k = kt * 32 + ((l >> 4) << 3) + e;
    int n = (nt << 4) + (l & 15);
    Bswz[tid] = f2b(Wg2[k * GH + n]);
    if (tid < NB * GH) S[tid] = 0.f;
  }
}

// ---------------------------------------------------------------------------
// MFMA pair GEMM v11. Block = 1024 thr (16 waves, wave grid 2m x 8n), tile =
// 128 pairs x 256 cols (B L2-traffic per FLOP halved vs 64-row tiles).
// Per wave: rows 64*wm + mf*16 (mf 0..3), cols 32*wn + nt*16 (nt 0..1):
// acc[4][2] = 32 regs, af 16, bfr 8, build 32 transient -> ~108 regs, fits
// the 128-reg cap from __launch_bounds__(1024,1) (16 waves/CU = 4/SIMD).
// LDS: A double-buffer 2 x 64 KB (128 KB/WG, legal on gfx950). 1 barrier per
// tile; build of tile t+1 (4 octet-units/thread, statically-indexed loads
// staged at tile start) interleaved at odd kt. XCD-pinned batches.
// Grid = 256 blocks (1/CU), ~20 tiles each.
// ---------------------------------------------------------------------------
__global__ __launch_bounds__(1024, 1) void pair_gemm(const u16* __restrict__ Lq,
                                                     const u16* __restrict__ R,
                                                     const u16* __restrict__ Bswz,
                                                     const float* __restrict__ bg2,
                                                     float* __restrict__ S) {
  const int bid = blockIdx.x;          // 0..255
  const int xcd = bid & 7;
  const int idx = bid >> 3;            // 0..31
  const int b   = xcd * 4 + (idx >> 3);
  const int bi  = idx & 7;             // 0..7, 162 tiles over 8 blocks
  const int t0  = bi * 20 + (bi < 2 ? bi : 2);
  const int cnt = 20 + (bi < 2 ? 1 : 0);

  // [kt 8][mf 8][lane 64][8 bf16] per buffer = 64 KB; x2 dbuf
  __shared__ __align__(16) u16 As[2][32768];

  const int t = threadIdx.x;
  const int w = t >> 6, l = t & 63;
  const int wn = w & 7, wm = w >> 3;
  // builder role: 128 rows x 8 cc; 4 octet-units per thread
  const int brow = t >> 3;             // 0..127
  const int cc   = t & 7;
  const int kb   = cc >> 2;            // kt parity
  const int oc   = cc & 3;             // octet within kt
  const int mf_w   = brow >> 4;
  const int lane_w = ((brow & 15) | (oc << 4)) ^ (oc << 1);  // 0-conflict (v8)
  const int lane_r = l ^ (((l >> 4) & 3) << 1);

  const u16* Lbase = Lq + b * NN * GH;
  const u16* Rbase = R + b * NN * GH;
  const u16* Bl    = Bswz + l * 8;

  float bgv[2];
#pragma unroll
  for (int nt = 0; nt < 2; ++nt)
    bgv[nt] = bg2[(wn << 5) + (nt << 4) + (l & 15)];
  float ssum[2] = {0.f, 0.f};

  // Prologue: build tile t0 fully into As[0]
  {
    int p = t0 * 128 + brow;
    int i = p / NN, j = p - i * NN;
    const u16* Lr = Lbase + i * GH + oc * 8;
    const u16* Rr = Rbase + j * GH + oc * 8;
#pragma unroll
    for (int q = 0; q < 4; ++q) {
      const int kt = kb + (q << 1);
      bf16x8 lv = *(const bf16x8*)(Lr + kt * 32);
      bf16x8 rv = *(const bf16x8*)(Rr + kt * 32);
      u16 o[8];
#pragma unroll
      for (int e = 0; e < 8; ++e) {
        float v = b2f((u16)lv[e]) + b2f((u16)rv[e]);
        o[e] = f2b(v > 0.f ? v : 0.f);
      }
      *(bf16x8*)&As[0][((((kt << 3) | mf_w) << 6) | lane_w) << 3] = *(bf16x8*)o;
    }
  }
  __syncthreads();

  for (int tt = 0; tt < cnt; ++tt) {
    const int  cur = tt & 1;
    const bool hb  = (tt + 1 < cnt);
    // stage all 8 build loads for tile tt+1 (32 regs, statically indexed)
    bf16x8 bl[4], br[4];
    if (hb) {
      int p = (t0 + tt + 1) * 128 + brow;
      int i = p / NN, j = p - i * NN;
      const u16* Lb = Lbase + i * GH + oc * 8;
      const u16* Rb = Rbase + j * GH + oc * 8;
#pragma unroll
      for (int q = 0; q < 4; ++q) {
        bl[q] = *(const bf16x8*)(Lb + (kb + (q << 1)) * 32);
        br[q] = *(const bf16x8*)(Rb + (kb + (q << 1)) * 32);
      }
    }
    f32x4 acc[4][2] = {};
#pragma unroll
    for (int kt = 0; kt < 8; ++kt) {
      // A fragments: this wave's 4 row-frags
      bf16x8 af[4];
#pragma unroll
      for (int mf = 0; mf < 4; ++mf)
        af[mf] = *(const bf16x8*)
            &As[cur][((((kt << 3) | (wm << 2) | mf) << 6) | lane_r) << 3];
      // B fragments: this wave's 2 col-frags (L2-resident)
      bf16x8 bfr[2];
#pragma unroll
      for (int nt = 0; nt < 2; ++nt) {
        int fid = (kt << 4) | (wn << 1) | nt;
        bfr[nt] = *(const bf16x8*)(Bl + ((size_t)fid << 9));
      }
      // interleaved build of tile tt+1 at odd kt (unit q = kt>>1, static)
      if (hb && (kt & 1)) {
        const int q   = kt >> 1;
        const int ktw = kb + (q << 1);
        u16 o[8];
#pragma unroll
        for (int e = 0; e < 8; ++e) {
          float v = b2f((u16)bl[q][e]) + b2f((u16)br[q][e]);
          o[e] = f2b(v > 0.f ? v : 0.f);
        }
        *(bf16x8*)&As[cur ^ 1][((((ktw << 3) | mf_w) << 6) | lane_w) << 3] =
            *(bf16x8*)o;
      }
      // 8 MFMAs
#pragma unroll
      for (int mf = 0; mf < 4; ++mf)
#pragma unroll
        for (int nt = 0; nt < 2; ++nt)
          acc[mf][nt] = __builtin_amdgcn_mfma_f32_16x16x32_bf16(
              af[mf], bfr[nt], acc[mf][nt], 0, 0, 0);
    }
    // per-tile epilogue: fold relu(acc + bg2) into running sums
#pragma unroll
    for (int nt = 0; nt < 2; ++nt) {
      float s = 0.f;
#pragma unroll
      for (int mf = 0; mf < 4; ++mf)
#pragma unroll
        for (int r = 0; r < 4; ++r) {
          float v = acc[mf][nt][r] + bgv[nt];
          s += v > 0.f ? v : 0.f;
        }
      ssum[nt] += s;
    }
    __syncthreads();
  }

  // Final reduce: C/D col = l&15; shfl-reduce rows, one atomic per col slice
  float* Sb = S + b * GH;
#pragma unroll
  for (int nt = 0; nt < 2; ++nt) {
    float s = ssum[nt];
    s += __shfl_xor(s, 16, 64);
    s += __shfl_xor(s, 32, 64);
    if (l < 16) atomicAdd(&Sb[(wn << 5) + (nt << 4) + l], s);
  }
}

// ---------------------------------------------------------------------------
// Final f-MLP: out = relu(S@Wf1+bf1)@Wf2+bf2. One block per batch.
// ---------------------------------------------------------------------------
__global__ __launch_bounds__(256) void final_mlp(const float* __restrict__ S,
                                                 const float* __restrict__ Wf1,
                                                 const float* __restrict__ bf1,
                                                 const float* __restrict__ Wf2,
                                                 const float* __restrict__ bf2,
                                                 float* __restrict__ out) {
  __shared__ float sS[GH];
  __shared__ float oS[GH];
  int b = blockIdx.x, h = threadIdx.x;
  sS[h] = S[b * GH + h];
  __syncthreads();
  float acc = bf1[h];
#pragma unroll 8
  for (int k = 0; k < GH; ++k) acc += sS[k] * Wf1[k * GH + h];
  oS[h] = acc > 0.f ? acc : 0.f;
  __syncthreads();
  if (h < FOUT) {
    float o = bf2[h];
#pragma unroll 8
    for (int k = 0; k < GH; ++k) o += oS[k] * Wf2[k * FOUT + h];
    out[b * FOUT + h] = o;
  }
}

extern "C" void kernel_launch(void* const* d_in, const int* in_sizes, int n_in,
                              void* d_out, int out_size, void* d_ws, size_t ws_size,
                              hipStream_t stream) {
  const float* image    = (const float*)d_in[0];
  const float* question = (const float*)d_in[1];
  const float* Wg1      = (const float*)d_in[2];
  const float* bg1      = (const float*)d_in[3];
  const float* Wg2      = (const float*)d_in[4];
  const float* bg2      = (const float*)d_in[5];
  const float* Wf1      = (const float*)d_in[6];
  const float* bf1      = (const float*)d_in[7];
  const float* Wf2      = (const float*)d_in[8];
  const float* bf2      = (const float*)d_in[9];
  float* out = (float*)d_out;

  u16*   wsb  = (u16*)d_ws;
  u16*   Lqp  = wsb + LQ_U16;
  u16*   Rp   = wsb + R_U16;
  u16*   Bswz = wsb + BS_U16;
  float* Sp   = (float*)((char*)d_ws + S_BYTE);

  prep<<<2 * NB * NN + 256, 256, 0, stream>>>(image, question, Wg1, bg1, Wg2,
                                              Lqp, Rp, Sp, Bswz);
  pair_gemm<<<256, 1024, 0, stream>>>(Lqp, Rp, Bswz, bg2, Sp);
  final_mlp<<<NB, 256, 0, stream>>>(Sp, Wf1, bf1, Wf2, bf2, out);
}

// Round 12
// 112.355 us; speedup vs baseline: 1.6952x; 1.6952x over previous
//
#include <hip/hip_runtime.h>
#include <hip/hip_bf16.h>

// Problem constants
#define NB   32      // batch
#define NC   24      // image channels
#define ND   12      // spatial
#define NN   144     // ND*ND objects
#define QD   11
#define GH   256
#define FOUT 10

typedef unsigned short u16;
typedef __attribute__((ext_vector_type(8))) short bf16x8;
typedef __attribute__((ext_vector_type(4))) float f32x4;

// Workspace layout (u16 units unless noted):
//   Lqb  u16 [32][144][256]  off 0          (= L + q@Wg1_q + bg1, bf16)
//   Rb   u16 [32][144][256]  off 1179648
//   Bswz u16 [128][64][8]    off 2359296    (MFMA B-fragment order)
//   S    f32 [32][256]       byte-off 4849664
#define LQ_U16  0
#define R_U16   1179648
#define BS_U16  2359296
#define S_BYTE  4849664

__device__ inline float b2f(u16 v) {
  union { unsigned u; float f; } c; c.u = ((unsigned)v) << 16; return c.f;
}
__device__ inline u16 f2b(float f) {
  __hip_bfloat16 h = __float2bfloat16(f);
  return *reinterpret_cast<u16*>(&h);
}

// ---------------------------------------------------------------------------
// Fused prep:
//  blocks [0, 9216): per-object projections -> bf16 (Lq folds q-term + bg1).
//  blocks [9216, 9472): Wg2 -> bf16 B-fragment swizzle; zero S.
// ---------------------------------------------------------------------------
__global__ __launch_bounds__(256) void prep(const float* __restrict__ image,
                                            const float* __restrict__ question,
                                            const float* __restrict__ Wg1,
                                            const float* __restrict__ bg1,
                                            const float* __restrict__ Wg2,
                                            u16* __restrict__ Lq,
                                            u16* __restrict__ R,
                                            float* __restrict__ S,
                                            u16* __restrict__ Bswz) {
  int blk = blockIdx.x;
  int h   = threadIdx.x;
  if (blk < 2 * NB * NN) {
    int p     = blk % NN;
    int rest2 = blk / NN;
    int b     = rest2 & (NB - 1);
    int which = rest2 >> 5;
    const float* Wrow = Wg1 + which * (NC + 2) * GH;
    const float* img  = image + b * (NC * NN) + p;
    float acc = 0.f;
#pragma unroll
    for (int c = 0; c < NC; ++c) acc += img[c * NN] * Wrow[c * GH + h];
    int i = p / ND, j = p - i * ND;
    const float inv = 1.0f / (ND - 1);
    acc += (j * inv) * Wrow[24 * GH + h];
    acc += (i * inv) * Wrow[25 * GH + h];
    if (which == 0) {
      acc += bg1[h];
#pragma unroll
      for (int tq = 0; tq < QD; ++tq)
        acc += question[b * QD + tq] * Wg1[(2 * (NC + 2) + tq) * GH + h];
      Lq[(b * NN + p) * GH + h] = f2b(acc);
    } else {
      R[(b * NN + p) * GH + h] = f2b(acc);
    }
  } else {
    int tid = (blk - 2 * NB * NN) * 256 + h;   // 0..65535
    int e   = tid & 7;
    int l   = (tid >> 3) & 63;
    int fid = tid >> 9;
    int kt  = fid >> 4, nt = fid & 15;
    int k = kt * 32 + ((l >> 4) << 3) + e;
    int n = (nt << 4) + (l & 15);
    Bswz[tid] = f2b(Wg2[k * GH + n]);
    if (tid < NB * GH) S[tid] = 0.f;
  }
}

// ---------------------------------------------------------------------------
// MFMA pair GEMM v12. Block = 512 thr (8 waves, wave-grid 2m x 4n), tile =
// 128 pairs x 256 cols. Registers fit by construction via PHASE-DISJOINT
// lifetimes: build phase peak ~55 regs (32 transient loads), MFMA phase peak
// ~114 (acc 64 + af 16 + bfr 16 + misc) -> both <= 128 cap from
// __launch_bounds__(512,2) (2 blocks/CU). Single 64 KB LDS buffer; per tile:
// [build | bar | MFMA + epilogue | bar]. Cross-block phase stagger (2
// independent blocks/CU) keeps the matrix pipe fed during builds.
// setprio(1) around MFMA groups (blocks at different phases -> T5 applies).
// Grid = 512 blocks XCD-pinned; ~10 tiles/block.
// ---------------------------------------------------------------------------
__global__ __launch_bounds__(512, 2) void pair_gemm(const u16* __restrict__ Lq,
                                                    const u16* __restrict__ R,
                                                    const u16* __restrict__ Bswz,
                                                    const float* __restrict__ bg2,
                                                    float* __restrict__ S) {
  const int bid = blockIdx.x;          // 0..511
  const int xcd = bid & 7;
  const int idx = bid >> 3;            // 0..63
  const int b   = xcd * 4 + (idx >> 4);
  const int bi  = idx & 15;            // 16 blocks per batch, 162 tiles
  const int t0  = bi * 10 + (bi < 2 ? bi : 2);
  const int cnt = 10 + (bi < 2 ? 1 : 0);

  // [kt 8][mf 8][lane 64][8 bf16] = 64 KB
  __shared__ __align__(16) u16 As[8 * 8 * 64 * 8];

  const int t = threadIdx.x;
  const int w = t >> 6, l = t & 63;
  const int wn = w & 3, wm = w >> 2;
  // builder role: row t>>2 (0..127), k-octet t&3; 8 units (one per kt)
  const int brow = t >> 2;
  const int oc   = t & 3;
  const int mf_w   = brow >> 4;                              // 0..7
  const int lane_w = ((brow & 15) | (oc << 4)) ^ (oc << 1);  // 2-way (free)
  const int lane_r = l ^ (((l >> 4) & 3) << 1);

  const u16* Lbase = Lq + b * NN * GH;
  const u16* Rbase = R + b * NN * GH;
  const u16* Bl    = Bswz + l * 8;

  float bgv[4];
#pragma unroll
  for (int nt = 0; nt < 4; ++nt)
    bgv[nt] = bg2[(wn << 6) + (nt << 4) + (l & 15)];
  float ssum[4] = {0.f, 0.f, 0.f, 0.f};

  for (int tt = 0; tt < cnt; ++tt) {
    // ---- build phase: whole 128x256 tile into LDS (two 4-kt batches) ----
    {
      int p = (t0 + tt) * 128 + brow;
      int i = p / NN, j = p - i * NN;
      const u16* Lr = Lbase + i * GH + oc * 8;
      const u16* Rr = Rbase + j * GH + oc * 8;
#pragma unroll
      for (int half = 0; half < 2; ++half) {
        bf16x8 lv[4], rv[4];
#pragma unroll
        for (int q = 0; q < 4; ++q) {
          lv[q] = *(const bf16x8*)(Lr + ((half << 2) | q) * 32);
          rv[q] = *(const bf16x8*)(Rr + ((half << 2) | q) * 32);
        }
#pragma unroll
        for (int q = 0; q < 4; ++q) {
          const int kt = (half << 2) | q;
          u16 o[8];
#pragma unroll
          for (int e = 0; e < 8; ++e) {
            float v = b2f((u16)lv[q][e]) + b2f((u16)rv[q][e]);
            o[e] = f2b(v > 0.f ? v : 0.f);
          }
          *(bf16x8*)&As[((((kt << 3) | mf_w) << 6) | lane_w) << 3] =
              *(bf16x8*)o;
        }
      }
    }
    __syncthreads();

    // ---- MFMA phase ----
    f32x4 acc[4][4] = {};
#pragma unroll
    for (int kt = 0; kt < 8; ++kt) {
      bf16x8 af[4];
#pragma unroll
      for (int mf = 0; mf < 4; ++mf)
        af[mf] = *(const bf16x8*)
            &As[((((kt << 3) | (wm << 2) | mf) << 6) | lane_r) << 3];
      bf16x8 bfr[4];
#pragma unroll
      for (int nt = 0; nt < 4; ++nt) {
        int fid = (kt << 4) | (wn << 2) | nt;
        bfr[nt] = *(const bf16x8*)(Bl + ((size_t)fid << 9));
      }
      __builtin_amdgcn_s_setprio(1);
#pragma unroll
      for (int mf = 0; mf < 4; ++mf)
#pragma unroll
        for (int nt = 0; nt < 4; ++nt)
          acc[mf][nt] = __builtin_amdgcn_mfma_f32_16x16x32_bf16(
              af[mf], bfr[nt], acc[mf][nt], 0, 0, 0);
      __builtin_amdgcn_s_setprio(0);
    }
    // epilogue: fold relu(acc + bg2) into running sums
#pragma unroll
    for (int nt = 0; nt < 4; ++nt) {
      float s = 0.f;
#pragma unroll
      for (int mf = 0; mf < 4; ++mf)
#pragma unroll
        for (int r = 0; r < 4; ++r) {
          float v = acc[mf][nt][r] + bgv[nt];
          s += v > 0.f ? v : 0.f;
        }
      ssum[nt] += s;
    }
    __syncthreads();
  }

  // Final reduce: C/D col = l&15; shfl-reduce rows, one atomic per col slice
  float* Sb = S + b * GH;
#pragma unroll
  for (int nt = 0; nt < 4; ++nt) {
    float s = ssum[nt];
    s += __shfl_xor(s, 16, 64);
    s += __shfl_xor(s, 32, 64);
    if (l < 16) atomicAdd(&Sb[(wn << 6) + (nt << 4) + l], s);
  }
}

// ---------------------------------------------------------------------------
// Final f-MLP: out = relu(S@Wf1+bf1)@Wf2+bf2. One block per batch.
// ---------------------------------------------------------------------------
__global__ __launch_bounds__(256) void final_mlp(const float* __restrict__ S,
                                                 const float* __restrict__ Wf1,
                                                 const float* __restrict__ bf1,
                                                 const float* __restrict__ Wf2,
                                                 const float* __restrict__ bf2,
                                                 float* __restrict__ out) {
  __shared__ float sS[GH];
  __shared__ float oS[GH];
  int b = blockIdx.x, h = threadIdx.x;
  sS[h] = S[b * GH + h];
  __syncthreads();
  float acc = bf1[h];
#pragma unroll 8
  for (int k = 0; k < GH; ++k) acc += sS[k] * Wf1[k * GH + h];
  oS[h] = acc > 0.f ? acc : 0.f;
  __syncthreads();
  if (h < FOUT) {
    float o = bf2[h];
#pragma unroll 8
    for (int k = 0; k < GH; ++k) o += oS[k] * Wf2[k * FOUT + h];
    out[b * FOUT + h] = o;
  }
}

extern "C" void kernel_launch(void* const* d_in, const int* in_sizes, int n_in,
                              void* d_out, int out_size, void* d_ws, size_t ws_size,
                              hipStream_t stream) {
  const float* image    = (const float*)d_in[0];
  const float* question = (const float*)d_in[1];
  const float* Wg1      = (const float*)d_in[2];
  const float* bg1      = (const float*)d_in[3];
  const float* Wg2      = (const float*)d_in[4];
  const float* bg2      = (const float*)d_in[5];
  const float* Wf1      = (const float*)d_in[6];
  const float* bf1      = (const float*)d_in[7];
  const float* Wf2      = (const float*)d_in[8];
  const float* bf2      = (const float*)d_in[9];
  float* out = (float*)d_out;

  u16*   wsb  = (u16*)d_ws;
  u16*   Lqp  = wsb + LQ_U16;
  u16*   Rp   = wsb + R_U16;
  u16*   Bswz = wsb + BS_U16;
  float* Sp   = (float*)((char*)d_ws + S_BYTE);

  prep<<<2 * NB * NN + 256, 256, 0, stream>>>(image, question, Wg1, bg1, Wg2,
                                              Lqp, Rp, Sp, Bswz);
  pair_gemm<<<512, 512, 0, stream>>>(Lqp, Rp, Bswz, bg2, Sp);
  final_mlp<<<NB, 256, 0, stream>>>(Sp, Wf1, bf1, Wf2, bf2, out);
}